// Round 1
// baseline (212.721 us; speedup 1.0000x reference)
//
#include <hip/hip_runtime.h>

typedef __bf16 bf16;
typedef __bf16 bf16x8 __attribute__((ext_vector_type(8)));
typedef __bf16 bf16x4 __attribute__((ext_vector_type(4)));
typedef float f32x4 __attribute__((ext_vector_type(4)));

#define GLOAD_LDS16(g, l)                                                     \
  __builtin_amdgcn_global_load_lds(                                           \
      (const __attribute__((address_space(1))) void*)(g),                     \
      (__attribute__((address_space(3))) void*)(l), 16, 0, 0)

// Swizzled LDS fragment read: 128B rows, byte ^= (row&7)<<4
__device__ inline bf16x8 lds_frag(const char* base, int row, int colb) {
  return *(const bf16x8*)(base + (row << 7) + (colb ^ ((row & 7) << 4)));
}

// ---------------- conversion kernels ----------------
__global__ __launch_bounds__(256) void cvt_x(const float* __restrict__ in,
                                             bf16* __restrict__ out) {
  int i = (blockIdx.x * 256 + threadIdx.x) * 4;
  float4 v = *(const float4*)(in + i);
  bf16x4 o;
  o[0] = (bf16)v.x; o[1] = (bf16)v.y; o[2] = (bf16)v.z; o[3] = (bf16)v.w;
  *(bf16x4*)(out + i) = o;
}

// out[c][r] = (bf16) in[r][c]
__global__ __launch_bounds__(256) void tconv(const float* __restrict__ in,
                                             bf16* __restrict__ out, int R, int C) {
  __shared__ float t[32][33];
  int c0 = blockIdx.x * 32, r0 = blockIdx.y * 32;
  int tx = threadIdx.x & 31, ty = threadIdx.x >> 5;
#pragma unroll
  for (int i = 0; i < 32; i += 8)
    t[ty + i][tx] = in[(size_t)(r0 + ty + i) * C + c0 + tx];
  __syncthreads();
#pragma unroll
  for (int i = 0; i < 32; i += 8)
    out[(size_t)(c0 + ty + i) * R + r0 + tx] = (bf16)t[tx][ty + i];
}

// ---------------- GEMM: C[M][N] = A[M][K] * Bt[N][K]^T + bias ----------------
template <typename OutT>
__global__ __launch_bounds__(256, 2) void gemm_bt(const bf16* __restrict__ A,
                                                  const bf16* __restrict__ Bt,
                                                  const float* __restrict__ bias,
                                                  OutT* __restrict__ C,
                                                  int M, int N, int K) {
  __shared__ __align__(16) char lsA[128 * 128];
  __shared__ __align__(16) char lsB[128 * 128];
  const int tid = threadIdx.x;
  const int lane = tid & 63, wid = tid >> 6;
  const int wr = wid >> 1, wc = wid & 1;
  const int l15 = lane & 15, lg = lane >> 4;
  const size_t tm = blockIdx.y * 128, tn = blockIdx.x * 128;
  const size_t Kb = (size_t)K * 2;
  const char* Ab = (const char*)A + tm * Kb;
  const char* Bb = (const char*)Bt + tn * Kb;
  f32x4 acc[4][4] = {};
  for (int kt = 0; kt < K; kt += 64) {
#pragma unroll
    for (int p = 0; p < 4; ++p) {
      int L = p * 4096 + tid * 16;
      int row = L >> 7, c = L & 127;
      int sc = c ^ ((row & 7) << 4);
      GLOAD_LDS16(Ab + (size_t)row * Kb + kt * 2 + sc, lsA + L);
      GLOAD_LDS16(Bb + (size_t)row * Kb + kt * 2 + sc, lsB + L);
    }
    __syncthreads();
#pragma unroll
    for (int kc = 0; kc < 2; ++kc) {
      bf16x8 af[4], bfr[4];
#pragma unroll
      for (int f = 0; f < 4; ++f) {
        af[f]  = lds_frag(lsA, wr * 64 + f * 16 + l15, kc * 64 + lg * 16);
        bfr[f] = lds_frag(lsB, wc * 64 + f * 16 + l15, kc * 64 + lg * 16);
      }
#pragma unroll
      for (int i = 0; i < 4; ++i)
#pragma unroll
        for (int j = 0; j < 4; ++j)
          acc[i][j] = __builtin_amdgcn_mfma_f32_16x16x32_bf16(af[i], bfr[j],
                                                              acc[i][j], 0, 0, 0);
    }
    __syncthreads();
  }
#pragma unroll
  for (int i = 0; i < 4; ++i) {
    size_t row = tm + wr * 64 + i * 16 + lg * 4;
#pragma unroll
    for (int j = 0; j < 4; ++j) {
      int col = (int)tn + wc * 64 + j * 16 + l15;
      float bv = bias[col];
#pragma unroll
      for (int r = 0; r < 4; ++r)
        C[(row + r) * N + col] = (OutT)(acc[i][j][r] + bv);
    }
  }
}

// ---------------- RMSNorm + RoPE + layout for attention ----------------
// qkv: [B*N][3072] bf16. Writes qb,kb: [B*H][N][64] (q pre-scaled by 1/8),
// vt: [B*H][64][N] (transposed).
__global__ __launch_bounds__(256) void rmsrope(const bf16* __restrict__ qkv,
                                               const float* __restrict__ cosb,
                                               const float* __restrict__ sinb,
                                               const float* __restrict__ qs,
                                               const float* __restrict__ ks,
                                               bf16* __restrict__ qb,
                                               bf16* __restrict__ kb,
                                               bf16* __restrict__ vt) {
  const int bn = blockIdx.x;  // b*2048 + n
  const int n = bn & 2047;
  const int b = bn >> 11;
  const int t = threadIdx.x;
  const bf16* row = qkv + (size_t)bn * 3072;
  bf16x4 q4 = *(const bf16x4*)(row + 4 * t);
  bf16x4 k4 = *(const bf16x4*)(row + 1024 + 4 * t);
  bf16x4 v4 = *(const bf16x4*)(row + 2048 + 4 * t);
  float q0 = (float)q4[0], q1 = (float)q4[1], q2 = (float)q4[2], q3 = (float)q4[3];
  float k0 = (float)k4[0], k1 = (float)k4[1], k2 = (float)k4[2], k3 = (float)k4[3];
  float sq = q0 * q0 + q1 * q1 + q2 * q2 + q3 * q3;
  float sk = k0 * k0 + k1 * k1 + k2 * k2 + k3 * k3;
#pragma unroll
  for (int m = 32; m >= 1; m >>= 1) {
    sq += __shfl_xor(sq, m);
    sk += __shfl_xor(sk, m);
  }
  __shared__ float rq[4], rk[4];
  const int w = t >> 6;
  if ((t & 63) == 0) { rq[w] = sq; rk[w] = sk; }
  __syncthreads();
  sq = rq[0] + rq[1] + rq[2] + rq[3];
  sk = rk[0] + rk[1] + rk[2] + rk[3];
  const float qn = rsqrtf(sq * (1.0f / 1024.0f) + 1e-6f);
  const float kn = rsqrtf(sk * (1.0f / 1024.0f) + 1e-6f);
  const int d4 = 4 * t;
  const int h = d4 >> 6, dd = d4 & 63;
  const int i0 = dd >> 1;
  const float c0 = cosb[n * 32 + i0], s0 = sinb[n * 32 + i0];
  const float c1 = cosb[n * 32 + i0 + 1], s1 = sinb[n * 32 + i0 + 1];
  float xq0 = q0 * qn * qs[d4], xq1 = q1 * qn * qs[d4 + 1];
  float xq2 = q2 * qn * qs[d4 + 2], xq3 = q3 * qn * qs[d4 + 3];
  float xk0 = k0 * kn * ks[d4], xk1 = k1 * kn * ks[d4 + 1];
  float xk2 = k2 * kn * ks[d4 + 2], xk3 = k3 * kn * ks[d4 + 3];
  bf16x4 qo, ko;
  qo[0] = (bf16)((xq0 * c0 - xq1 * s0) * 0.125f);
  qo[1] = (bf16)((xq0 * s0 + xq1 * c0) * 0.125f);
  qo[2] = (bf16)((xq2 * c1 - xq3 * s1) * 0.125f);
  qo[3] = (bf16)((xq2 * s1 + xq3 * c1) * 0.125f);
  ko[0] = (bf16)(xk0 * c0 - xk1 * s0);
  ko[1] = (bf16)(xk0 * s0 + xk1 * c0);
  ko[2] = (bf16)(xk2 * c1 - xk3 * s1);
  ko[3] = (bf16)(xk2 * s1 + xk3 * c1);
  size_t base = ((size_t)(b * 16 + h) * 2048 + n) * 64 + dd;
  *(bf16x4*)(qb + base) = qo;
  *(bf16x4*)(kb + base) = ko;
  size_t vb = ((size_t)(b * 16 + h) * 64 + dd) * 2048 + n;
  vt[vb] = v4[0];
  vt[vb + 2048] = v4[1];
  vt[vb + 2 * 2048] = v4[2];
  vt[vb + 3 * 2048] = v4[3];
}

// ---------------- flash attention ----------------
// qb,kb: [B*H][2048][64] (q pre-scaled), vt: [B*H][64][2048], ao: [B][2048][1024]
__global__ __launch_bounds__(256, 2) void attn(const bf16* __restrict__ qb,
                                               const bf16* __restrict__ kb,
                                               const bf16* __restrict__ vt,
                                               bf16* __restrict__ ao) {
  const int qt = blockIdx.x, bh = blockIdx.y;
  const int b = bh >> 4, h = bh & 15;
  const int tid = threadIdx.x;
  const int lane = tid & 63, w = tid >> 6;
  const int l15 = lane & 15, lg = lane >> 4;
  __shared__ __align__(16) char lsK[64 * 128];
  __shared__ __align__(16) char lsV[64 * 128];  // V^T tile: [d][kv]
  __shared__ __align__(16) char lsP[4][16 * 128];
  const int qrow = qt * 64 + w * 16 + l15;
  const bf16* qptr = qb + ((size_t)bh * 2048 + qrow) * 64 + lg * 8;
  bf16x8 qf0 = *(const bf16x8*)(qptr);
  bf16x8 qf1 = *(const bf16x8*)(qptr + 32);
  f32x4 o[4] = {};
  float mrow[4] = {-1e30f, -1e30f, -1e30f, -1e30f};
  float lrow[4] = {0.f, 0.f, 0.f, 0.f};
  const char* Kb = (const char*)(kb + (size_t)bh * 2048 * 64);
  const char* Vb = (const char*)(vt + (size_t)bh * 64 * 2048);
  for (int kv0 = 0; kv0 < 2048; kv0 += 64) {
#pragma unroll
    for (int p = 0; p < 2; ++p) {
      int L = p * 4096 + tid * 16;
      int row = L >> 7, c = L & 127;
      int sc = c ^ ((row & 7) << 4);
      GLOAD_LDS16(Kb + (size_t)(kv0 + row) * 128 + sc, lsK + L);
      GLOAD_LDS16(Vb + (size_t)row * 4096 + kv0 * 2 + sc, lsV + L);
    }
    __syncthreads();
    // S = Q * K^T  (16 q-rows x 64 k-cols per wave)
    f32x4 s[4];
#pragma unroll
    for (int nf = 0; nf < 4; ++nf) {
      bf16x8 kf0 = lds_frag(lsK, nf * 16 + l15, lg * 16);
      bf16x8 kf1 = lds_frag(lsK, nf * 16 + l15, 64 + lg * 16);
      f32x4 z = {0.f, 0.f, 0.f, 0.f};
      z = __builtin_amdgcn_mfma_f32_16x16x32_bf16(qf0, kf0, z, 0, 0, 0);
      z = __builtin_amdgcn_mfma_f32_16x16x32_bf16(qf1, kf1, z, 0, 0, 0);
      s[nf] = z;
    }
    // online softmax (row r lives on the 16 lanes of this lane-group)
    float nm[4], sc_[4];
#pragma unroll
    for (int r = 0; r < 4; ++r) {
      float mx = fmaxf(fmaxf(s[0][r], s[1][r]), fmaxf(s[2][r], s[3][r]));
#pragma unroll
      for (int m = 1; m < 16; m <<= 1) mx = fmaxf(mx, __shfl_xor(mx, m));
      nm[r] = fmaxf(mrow[r], mx);
      sc_[r] = __expf(mrow[r] - nm[r]);
      mrow[r] = nm[r];
    }
#pragma unroll
    for (int nf = 0; nf < 4; ++nf)
#pragma unroll
      for (int r = 0; r < 4; ++r) s[nf][r] = __expf(s[nf][r] - nm[r]);
#pragma unroll
    for (int r = 0; r < 4; ++r) {
      float sum = s[0][r] + s[1][r] + s[2][r] + s[3][r];
#pragma unroll
      for (int m = 1; m < 16; m <<= 1) sum += __shfl_xor(sum, m);
      lrow[r] = lrow[r] * sc_[r] + sum;
#pragma unroll
      for (int nf = 0; nf < 4; ++nf) o[nf][r] *= sc_[r];
    }
    // P -> per-wave LDS (bf16, swizzled) to reach A-fragment layout
    char* P = (char*)lsP[w];
#pragma unroll
    for (int nf = 0; nf < 4; ++nf)
#pragma unroll
      for (int r = 0; r < 4; ++r) {
        int rr = lg * 4 + r;
        int cb = (nf * 16 + l15) * 2;
        *(bf16*)(P + (rr << 7) + (cb ^ ((rr & 7) << 4))) = (bf16)s[nf][r];
      }
    asm volatile("s_waitcnt lgkmcnt(0)" ::: "memory");
    // O += P * V
#pragma unroll
    for (int kc = 0; kc < 2; ++kc) {
      bf16x8 pa = lds_frag(P, l15, kc * 64 + lg * 16);
#pragma unroll
      for (int df = 0; df < 4; ++df) {
        bf16x8 vf = lds_frag(lsV, df * 16 + l15, kc * 64 + lg * 16);
        o[df] = __builtin_amdgcn_mfma_f32_16x16x32_bf16(pa, vf, o[df], 0, 0, 0);
      }
    }
    __syncthreads();
  }
#pragma unroll
  for (int df = 0; df < 4; ++df)
#pragma unroll
    for (int r = 0; r < 4; ++r) {
      int qr = qt * 64 + w * 16 + lg * 4 + r;
      float val = o[df][r] / lrow[r];
      ao[((size_t)b * 2048 + qr) * 1024 + h * 64 + df * 16 + l15] = (bf16)val;
    }
}

// ---------------- launch ----------------
extern "C" void kernel_launch(void* const* d_in, const int* in_sizes, int n_in,
                              void* d_out, int out_size, void* d_ws, size_t ws_size,
                              hipStream_t stream) {
  const float* x    = (const float*)d_in[0];
  const float* cosb = (const float*)d_in[1];
  const float* sinb = (const float*)d_in[2];
  const float* Wqkv = (const float*)d_in[3];
  const float* bqkv = (const float*)d_in[4];
  const float* qs   = (const float*)d_in[5];
  const float* ks   = (const float*)d_in[6];
  const float* Wout = (const float*)d_in[7];
  const float* bout = (const float*)d_in[8];
  float* out = (float*)d_out;
  char* ws = (char*)d_ws;
  bf16* xb    = (bf16*)(ws);             // 8,388,608 B  : x bf16 [4096][1024]
  bf16* wqkvt = (bf16*)(ws + 8388608);   // 6,291,456 B  : Wqkv^T [3072][1024]
  bf16* woutt = (bf16*)(ws + 14680064);  // 2,097,152 B  : Wout^T [1024][1024]
  bf16* qkvb  = (bf16*)(ws + 16777216);  // 25,165,824 B : qkv bf16 [4096][3072]
  bf16* qb    = (bf16*)(ws + 41943040);  // 8,388,608 B  : [32][2048][64]
  bf16* kb    = (bf16*)(ws + 50331648);  // 8,388,608 B
  bf16* vt    = (bf16*)(ws + 58720256);  // 8,388,608 B  : [32][64][2048]
  bf16* ao    = (bf16*)(ws + 67108864);  // 8,388,608 B  : [4096][1024]

  cvt_x<<<4096, 256, 0, stream>>>(x, xb);
  tconv<<<dim3(96, 32), 256, 0, stream>>>(Wqkv, wqkvt, 1024, 3072);
  tconv<<<dim3(32, 32), 256, 0, stream>>>(Wout, woutt, 1024, 1024);
  gemm_bt<bf16><<<dim3(24, 32), 256, 0, stream>>>(xb, wqkvt, bqkv, qkvb,
                                                  4096, 3072, 1024);
  rmsrope<<<4096, 256, 0, stream>>>(qkvb, cosb, sinb, qs, ks, qb, kb, vt);
  attn<<<dim3(32, 32), 256, 0, stream>>>(qb, kb, vt, ao);
  gemm_bt<float><<<dim3(8, 32), 256, 0, stream>>>(ao, woutt, bout, out,
                                                  4096, 1024, 1024);
}